// Round 5
// baseline (174.004 us; speedup 1.0000x reference)
//
#include <hip/hip_runtime.h>
#include <math.h>

#define BB   2
#define LL   1024
#define DD   1024
#define HH   16
#define HDIM 64
#define MM   (BB * LL)     // 2048
#define CHK  64            // chunk length
#define NCHK (LL / CHK)    // 16

typedef short bf16x8 __attribute__((ext_vector_type(8)));
typedef float f32x4  __attribute__((ext_vector_type(4)));
typedef const __attribute__((address_space(1))) unsigned int* gas_ptr;
typedef __attribute__((address_space(3))) unsigned int* las_ptr;

__device__ __forceinline__ void gload16(const void* g, void* l) {
    __builtin_amdgcn_global_load_lds((gas_ptr)(unsigned long long)g,
                                     (las_ptr)(unsigned long long)l, 16, 0, 0);
}

__device__ __forceinline__ unsigned short f2bf(float f) {
    unsigned int u = __float_as_uint(f);
    u += 0x7fffu + ((u >> 16) & 1u);      // RNE
    return (unsigned short)(u >> 16);
}
__device__ __forceinline__ float bfhi(unsigned int u) { return __uint_as_float(u & 0xffff0000u); }
__device__ __forceinline__ float bflo(unsigned int u) { return __uint_as_float(u << 16); }

// 8 bf16 from a [64][70]-strided LDS tile at [row][tc..tc+7]; 4-aligned -> 4x b32
__device__ __forceinline__ bf16x8 frag70(const unsigned short* a, int row, int tc) {
    const unsigned int* p = (const unsigned int*)(a + row * 70 + tc);
    union { unsigned int u[4]; bf16x8 v; } r;
    r.u[0] = p[0]; r.u[1] = p[1]; r.u[2] = p[2]; r.u[3] = p[3];
    return r.v;
}

// ---------------------------------------------------------------------------
// prep_all: [0,2048) x cast fp32->bf16; [2048,2112) Wb -> Wbt bf16 [h][k];
// [2112,6208) transpose+cast Wq/Wk/Wv/Wo fp32 [k][n] -> bf16 [n][k].
// ---------------------------------------------------------------------------
__global__ void prep_all(const float* __restrict__ x, unsigned short* __restrict__ xb,
                         const float* __restrict__ Wb, unsigned short* __restrict__ Wbt,
                         const float* __restrict__ W0, const float* __restrict__ W1,
                         const float* __restrict__ W2, const float* __restrict__ W3,
                         unsigned short* __restrict__ T0, unsigned short* __restrict__ T1,
                         unsigned short* __restrict__ T2, unsigned short* __restrict__ T3) {
    const int bid = blockIdx.x;
    if (bid < 2048) {
        const int idx = bid * 256 + threadIdx.x;
        const float4 v = ((const float4*)x)[idx];
        ushort4 o;
        o.x = f2bf(v.x); o.y = f2bf(v.y); o.z = f2bf(v.z); o.w = f2bf(v.w);
        ((ushort4*)xb)[idx] = o;
        return;
    }
    if (bid < 2112) {
        const int t = (bid - 2048) * 256 + threadIdx.x;   // h-major [h][k]
        const int h = t >> 10, kidx = t & 1023;
        Wbt[t] = f2bf(Wb[kidx * HH + h]);
        return;
    }
    __shared__ float tile[32][33];
    const int b4 = bid - 2112;
    const int which = b4 >> 10;
    const int b = b4 & 1023;
    const int bk = b >> 5, bn = b & 31;
    const float* W = which == 0 ? W0 : which == 1 ? W1 : which == 2 ? W2 : W3;
    unsigned short* T = which == 0 ? T0 : which == 1 ? T1 : which == 2 ? T2 : T3;
    const int tx = threadIdx.x & 31, ty = threadIdx.x >> 5;
#pragma unroll
    for (int i = 0; i < 4; ++i)
        tile[ty + i * 8][tx] = W[(size_t)(bk * 32 + ty + i * 8) * DD + bn * 32 + tx];
    __syncthreads();
#pragma unroll
    for (int i = 0; i < 4; ++i)
        T[(size_t)(bn * 32 + ty + i * 8) * DD + bk * 32 + tx] = f2bf(tile[tx][ty + i * 8]);
}

// ---------------------------------------------------------------------------
// bf16 MFMA GEMM K-loop (m97 structure): 128x128 tile, BK=32, 256 thr.
// ---------------------------------------------------------------------------
__device__ __forceinline__ void gemm_kloop(const unsigned short* A, const unsigned short* Bt,
                                           unsigned short* As, unsigned short* Bs,
                                           int rowBase, int colBase, int K,
                                           f32x4 acc[4][4]) {
    const int tid = threadIdx.x;
    const int c0 = tid, c1 = tid + 256;
    const int ar0 = c0 >> 2, ak0 = (c0 & 3) << 3;
    const int ar1 = c1 >> 2, ak1 = (c1 & 3) << 3;
    const unsigned short* Ag0 = A + (size_t)(rowBase + ar0) * K + ak0;
    const unsigned short* Ag1 = A + (size_t)(rowBase + ar1) * K + ak1;
    const unsigned short* Bg0 = Bt + (size_t)(colBase + ar0) * K + ak0;
    const unsigned short* Bg1 = Bt + (size_t)(colBase + ar1) * K + ak1;
    unsigned short* Al0 = As + c0 * 8; unsigned short* Al1 = As + c1 * 8;
    unsigned short* Bl0 = Bs + c0 * 8; unsigned short* Bl1 = Bs + c1 * 8;
    const int lane = tid & 63, wv = tid >> 6;
    const int qr = wv >> 1, qc = wv & 1;
    const int fr = lane & 15;
    const int koff = (lane >> 4) << 3;
    int aoff[4], boff[4];
#pragma unroll
    for (int mi = 0; mi < 4; ++mi) aoff[mi] = (qr * 64 + mi * 16 + fr) * 32 + koff;
#pragma unroll
    for (int nj = 0; nj < 4; ++nj) boff[nj] = (qc * 64 + nj * 16 + fr) * 32 + koff;

    for (int k0 = 0; k0 < K; k0 += 32) {
        __syncthreads();
        gload16(Ag0, Al0); gload16(Ag1, Al1);
        gload16(Bg0, Bl0); gload16(Bg1, Bl1);
        Ag0 += 32; Ag1 += 32; Bg0 += 32; Bg1 += 32;
        __syncthreads();
        bf16x8 av[4], bv[4];
#pragma unroll
        for (int mi = 0; mi < 4; ++mi) av[mi] = *(const bf16x8*)(As + aoff[mi]);
#pragma unroll
        for (int nj = 0; nj < 4; ++nj) bv[nj] = *(const bf16x8*)(Bs + boff[nj]);
#pragma unroll
        for (int mi = 0; mi < 4; ++mi)
#pragma unroll
            for (int nj = 0; nj < 4; ++nj)
                acc[mi][nj] = __builtin_amdgcn_mfma_f32_16x16x32_bf16(av[mi], bv[nj], acc[mi][nj], 0, 0, 0);
    }
}

// ---------------------------------------------------------------------------
// Fused q/k/v projection GEMM (+L2-norm epilogue for q,k) AND beta mini-GEMM.
// blocks [0,384): qkv; blocks [384,400): beta = sigmoid(x@Wb+bb), MFMA from
// global (no LDS), Wbt bf16 [h][k].
// ---------------------------------------------------------------------------
__global__ __launch_bounds__(256) void gemm_qkv_beta(const unsigned short* __restrict__ xb,
                                                     const unsigned short* __restrict__ Wqt,
                                                     const unsigned short* __restrict__ Wkt,
                                                     const unsigned short* __restrict__ Wvt,
                                                     const unsigned short* __restrict__ Wbt,
                                                     const float* __restrict__ bbp,
                                                     unsigned short* __restrict__ qb,
                                                     unsigned short* __restrict__ kb,
                                                     unsigned short* __restrict__ vb,
                                                     float* __restrict__ beta) {
    __shared__ unsigned short As[128 * 32];
    __shared__ unsigned short Bs[128 * 32];
    const int lane = threadIdx.x & 63, wv = threadIdx.x >> 6;
    const int fr = lane & 15, quad = lane >> 4;
    if (blockIdx.x >= 384) {
        // ---- beta path: 16 blocks, 128 rows each, pure-register MFMA ----
        const int rowBase = (blockIdx.x - 384) * 128;
        const int r0 = rowBase + wv * 32 + fr;
        f32x4 bacc[2];
        bacc[0] = (f32x4){0.f, 0.f, 0.f, 0.f};
        bacc[1] = (f32x4){0.f, 0.f, 0.f, 0.f};
        for (int k0 = 0; k0 < DD; k0 += 32) {
            const int kk = k0 + quad * 8;
            const bf16x8 a0 = *(const bf16x8*)&xb[(size_t)r0 * DD + kk];
            const bf16x8 a1 = *(const bf16x8*)&xb[(size_t)(r0 + 16) * DD + kk];
            const bf16x8 bw = *(const bf16x8*)&Wbt[(size_t)fr * DD + kk];
            bacc[0] = __builtin_amdgcn_mfma_f32_16x16x32_bf16(a0, bw, bacc[0], 0, 0, 0);
            bacc[1] = __builtin_amdgcn_mfma_f32_16x16x32_bf16(a1, bw, bacc[1], 0, 0, 0);
        }
        const float bias = bbp[fr];
#pragma unroll
        for (int mi = 0; mi < 2; ++mi)
#pragma unroll
            for (int i = 0; i < 4; ++i) {
                const int row = rowBase + wv * 32 + mi * 16 + quad * 4 + i;
                const float s = bacc[mi][i] + bias;
                beta[row * HH + fr] = 1.0f / (1.0f + expf(-s));
            }
        return;
    }
    // ---- qkv path ----
    const int by = blockIdx.x / 24, bxx = blockIdx.x % 24;
    const int mat = bxx >> 3, tn = bxx & 7;
    const unsigned short* Bt = mat == 0 ? Wqt : (mat == 1 ? Wkt : Wvt);
    unsigned short* Cout = mat == 0 ? qb : (mat == 1 ? kb : vb);
    f32x4 acc[4][4];
#pragma unroll
    for (int mi = 0; mi < 4; ++mi)
#pragma unroll
        for (int nj = 0; nj < 4; ++nj) acc[mi][nj] = (f32x4){0.f, 0.f, 0.f, 0.f};
    gemm_kloop(xb, Bt, As, Bs, by * 128, tn * 128, DD, acc);

    const int qr = wv >> 1, qc = wv & 1;
    if (mat < 2) {
#pragma unroll
        for (int mi = 0; mi < 4; ++mi)
#pragma unroll
            for (int i = 0; i < 4; ++i) {
                float s = 0.f;
#pragma unroll
                for (int nj = 0; nj < 4; ++nj) { float t = acc[mi][nj][i]; s += t * t; }
                s += __shfl_xor(s, 1, 64);
                s += __shfl_xor(s, 2, 64);
                s += __shfl_xor(s, 4, 64);
                s += __shfl_xor(s, 8, 64);
                const float inv = 1.0f / fmaxf(sqrtf(s), 1e-12f);
#pragma unroll
                for (int nj = 0; nj < 4; ++nj) acc[mi][nj][i] *= inv;
            }
    }
#pragma unroll
    for (int mi = 0; mi < 4; ++mi)
#pragma unroll
        for (int i = 0; i < 4; ++i) {
            const int row = by * 128 + qr * 64 + mi * 16 + quad * 4 + i;
#pragma unroll
            for (int nj = 0; nj < 4; ++nj) {
                const int col = tn * 128 + qc * 64 + nj * 16 + fr;
                Cout[(size_t)row * DD + col] = f2bf(acc[mi][nj][i]);
            }
        }
}

// ---------------------------------------------------------------------------
// Fused causal linear-attention scan. One block per (b,h); state (64x64 fp32)
// lives in MFMA accumulators across the 16-chunk sequential loop.
// Per chunk: dump state->sT(bf16), stage q/k/(beta*v); S=q@k^T, mask->P;
// O = P@vT + q@sT -> y;  state += k^T@vT.
// ---------------------------------------------------------------------------
__global__ __launch_bounds__(256) void scan_kernel(const unsigned short* __restrict__ q,
                                                   const unsigned short* __restrict__ k,
                                                   const unsigned short* __restrict__ v,
                                                   const float* __restrict__ beta,
                                                   unsigned short* __restrict__ y) {
    const int bh = blockIdx.x;
    const int b = bh >> 4, h = bh & 15;
    __shared__ unsigned short qS[64 * 80];   // [t][d]
    __shared__ unsigned short kS[64 * 80];   // [s][d]
    __shared__ unsigned short pS[64 * 80];   // masked P [t][s]
    __shared__ unsigned short kT[64 * 70];   // k^T [d][t] (unweighted)
    __shared__ unsigned short vT[64 * 70];   // (beta*v)^T [e][s]
    __shared__ unsigned short sT[64 * 70];   // state^T [e][d] bf16
    const int tid = threadIdx.x;
    const int lane = tid & 63, wv = tid >> 6;
    const int fr = lane & 15, quad = lane >> 4;
    // state: thread holds d = wv*16+quad*4+i, e = et*16+fr
    f32x4 st[4];
#pragma unroll
    for (int et = 0; et < 4; ++et) st[et] = (f32x4){0.f, 0.f, 0.f, 0.f};

    for (int c = 0; c < NCHK; ++c) {
        __syncthreads();   // prior chunk's LDS reads complete
        // dump state (pre-chunk value) to sT
#pragma unroll
        for (int et = 0; et < 4; ++et)
#pragma unroll
            for (int i = 0; i < 4; ++i)
                sT[(et * 16 + fr) * 70 + wv * 16 + quad * 4 + i] = f2bf(st[et][i]);
        // stage chunk
#pragma unroll
        for (int i2 = tid; i2 < 512; i2 += 256) {
            const int t = i2 >> 3, dg = (i2 & 7) << 3;
            const int m = b * LL + c * CHK + t;
            const float be = beta[m * HH + h];
            const size_t go = (size_t)m * DD + h * 64 + dg;
            const uint4 qu = *(const uint4*)&q[go];
            const uint4 ku = *(const uint4*)&k[go];
            const uint4 vu = *(const uint4*)&v[go];
            *(uint4*)&qS[t * 80 + dg] = qu;
            *(uint4*)&kS[t * 80 + dg] = ku;
            const unsigned int kw[4] = {ku.x, ku.y, ku.z, ku.w};
            const unsigned int vw[4] = {vu.x, vu.y, vu.z, vu.w};
#pragma unroll
            for (int jj = 0; jj < 4; ++jj) {
                kT[(dg + 2 * jj)     * 70 + t] = (unsigned short)(kw[jj] & 0xffffu);
                kT[(dg + 2 * jj + 1) * 70 + t] = (unsigned short)(kw[jj] >> 16);
                vT[(dg + 2 * jj)     * 70 + t] = f2bf(bflo(vw[jj]) * be);
                vT[(dg + 2 * jj + 1) * 70 + t] = f2bf(bfhi(vw[jj]) * be);
            }
        }
        __syncthreads();
        // S = q @ k^T (wave wv owns row-tile wv*16..+15)
        f32x4 sacc[4];
#pragma unroll
        for (int j = 0; j < 4; ++j) sacc[j] = (f32x4){0.f, 0.f, 0.f, 0.f};
#pragma unroll
        for (int kh = 0; kh < 2; ++kh) {
            const bf16x8 a = *(const bf16x8*)&qS[(wv * 16 + fr) * 80 + kh * 32 + quad * 8];
#pragma unroll
            for (int j = 0; j < 4; ++j) {
                const bf16x8 bbf = *(const bf16x8*)&kS[(j * 16 + fr) * 80 + kh * 32 + quad * 8];
                sacc[j] = __builtin_amdgcn_mfma_f32_16x16x32_bf16(a, bbf, sacc[j], 0, 0, 0);
            }
        }
        // mask -> P (rows written == rows this wave reads: no barrier)
#pragma unroll
        for (int j = 0; j < 4; ++j)
#pragma unroll
            for (int i = 0; i < 4; ++i) {
                const int t = wv * 16 + quad * 4 + i;
                const int s = j * 16 + fr;
                pS[t * 80 + s] = (s <= t) ? f2bf(sacc[j][i]) : (unsigned short)0;
            }
        // O = P @ vT + q @ sT
        f32x4 oacc[4];
#pragma unroll
        for (int j = 0; j < 4; ++j) oacc[j] = (f32x4){0.f, 0.f, 0.f, 0.f};
#pragma unroll
        for (int kh = 0; kh < 2; ++kh) {
            const bf16x8 a = *(const bf16x8*)&pS[(wv * 16 + fr) * 80 + kh * 32 + quad * 8];
#pragma unroll
            for (int j = 0; j < 4; ++j) {
                const bf16x8 bbf = frag70(vT, j * 16 + fr, kh * 32 + quad * 8);
                oacc[j] = __builtin_amdgcn_mfma_f32_16x16x32_bf16(a, bbf, oacc[j], 0, 0, 0);
            }
        }
#pragma unroll
        for (int kh = 0; kh < 2; ++kh) {
            const bf16x8 a = *(const bf16x8*)&qS[(wv * 16 + fr) * 80 + kh * 32 + quad * 8];
#pragma unroll
            for (int j = 0; j < 4; ++j) {
                const bf16x8 bbf = frag70(sT, j * 16 + fr, kh * 32 + quad * 8);
                oacc[j] = __builtin_amdgcn_mfma_f32_16x16x32_bf16(a, bbf, oacc[j], 0, 0, 0);
            }
        }
        // write y
#pragma unroll
        for (int j = 0; j < 4; ++j)
#pragma unroll
            for (int i = 0; i < 4; ++i) {
                const int m = b * LL + c * CHK + wv * 16 + quad * 4 + i;
                y[(size_t)m * DD + h * 64 + j * 16 + fr] = f2bf(oacc[j][i]);
            }
        // state += k^T @ vT  (A rows = d-tile wv*16)
#pragma unroll
        for (int kh = 0; kh < 2; ++kh) {
            const bf16x8 a = frag70(kT, wv * 16 + fr, kh * 32 + quad * 8);
#pragma unroll
            for (int et = 0; et < 4; ++et) {
                const bf16x8 bbf = frag70(vT, et * 16 + fr, kh * 32 + quad * 8);
                st[et] = __builtin_amdgcn_mfma_f32_16x16x32_bf16(a, bbf, st[et], 0, 0, 0);
            }
        }
    }
}

// ---------------------------------------------------------------------------
// Output GEMM: out = y(bf16) @ Wo -> fp32. 64x128 tile, grid = 32*8 = 256.
// ---------------------------------------------------------------------------
__global__ __launch_bounds__(256) void gemm_out(const unsigned short* __restrict__ yb,
                                                const unsigned short* __restrict__ Wot,
                                                float* __restrict__ out) {
    __shared__ unsigned short As[64 * 32];
    __shared__ unsigned short Bs[128 * 32];
    const int by = blockIdx.x >> 3, tn = blockIdx.x & 7;
    const int tid = threadIdx.x;
    const int rowBase = by * 64, colBase = tn * 128;
    const int ar = tid >> 2, ak = (tid & 3) << 3;
    const unsigned short* Ag = yb + (size_t)(rowBase + ar) * DD + ak;
    unsigned short* Al = As + tid * 8;
    const int c1 = tid + 256;
    const int br1 = c1 >> 2, bk1 = (c1 & 3) << 3;
    const unsigned short* Bg0 = Wot + (size_t)(colBase + ar) * DD + ak;
    const unsigned short* Bg1 = Wot + (size_t)(colBase + br1) * DD + bk1;
    unsigned short* Bl0 = Bs + tid * 8; unsigned short* Bl1 = Bs + c1 * 8;
    const int lane = tid & 63, wv = tid >> 6;
    const int rh = wv & 1, ch = wv >> 1;
    const int fr = lane & 15, koff = (lane >> 4) << 3;
    int aoff[2], boff[4];
#pragma unroll
    for (int mi = 0; mi < 2; ++mi) aoff[mi] = (rh * 32 + mi * 16 + fr) * 32 + koff;
#pragma unroll
    for (int nj = 0; nj < 4; ++nj) boff[nj] = (ch * 64 + nj * 16 + fr) * 32 + koff;
    f32x4 acc[2][4];
#pragma unroll
    for (int mi = 0; mi < 2; ++mi)
#pragma unroll
        for (int nj = 0; nj < 4; ++nj) acc[mi][nj] = (f32x4){0.f, 0.f, 0.f, 0.f};
    for (int k0 = 0; k0 < DD; k0 += 32) {
        __syncthreads();
        gload16(Ag, Al); gload16(Bg0, Bl0); gload16(Bg1, Bl1);
        Ag += 32; Bg0 += 32; Bg1 += 32;
        __syncthreads();
        bf16x8 av[2], bv[4];
#pragma unroll
        for (int mi = 0; mi < 2; ++mi) av[mi] = *(const bf16x8*)(As + aoff[mi]);
#pragma unroll
        for (int nj = 0; nj < 4; ++nj) bv[nj] = *(const bf16x8*)(Bs + boff[nj]);
#pragma unroll
        for (int mi = 0; mi < 2; ++mi)
#pragma unroll
            for (int nj = 0; nj < 4; ++nj)
                acc[mi][nj] = __builtin_amdgcn_mfma_f32_16x16x32_bf16(av[mi], bv[nj], acc[mi][nj], 0, 0, 0);
    }
    const int quad = lane >> 4;
#pragma unroll
    for (int mi = 0; mi < 2; ++mi)
#pragma unroll
        for (int i = 0; i < 4; ++i) {
            const int row = rowBase + rh * 32 + mi * 16 + quad * 4 + i;
#pragma unroll
            for (int nj = 0; nj < 4; ++nj) {
                const int col = colBase + ch * 64 + nj * 16 + fr;
                out[(size_t)row * DD + col] = acc[mi][nj][i];
            }
        }
}

// ---------------------------------------------------------------------------
extern "C" void kernel_launch(void* const* d_in, const int* in_sizes, int n_in,
                              void* d_out, int out_size, void* d_ws, size_t ws_size,
                              hipStream_t stream) {
    (void)in_sizes; (void)n_in; (void)out_size; (void)ws_size;
    const float* x  = (const float*)d_in[0];
    const float* Wq = (const float*)d_in[1];
    const float* Wk = (const float*)d_in[2];
    const float* Wv = (const float*)d_in[3];
    const float* Wo = (const float*)d_in[4];
    const float* Wb = (const float*)d_in[5];
    const float* bbp = (const float*)d_in[6];
    float* out = (float*)d_out;

    char* ws = (char*)d_ws;
    unsigned short* xb  = (unsigned short*)ws;                      ws += (size_t)MM * DD * 2;
    unsigned short* Wqt = (unsigned short*)ws;                      ws += (size_t)DD * DD * 2;
    unsigned short* Wkt = (unsigned short*)ws;                      ws += (size_t)DD * DD * 2;
    unsigned short* Wvt = (unsigned short*)ws;                      ws += (size_t)DD * DD * 2;
    unsigned short* Wot = (unsigned short*)ws;                      ws += (size_t)DD * DD * 2;
    unsigned short* Wbt = (unsigned short*)ws;                      ws += (size_t)HH * DD * 2;
    unsigned short* qb  = (unsigned short*)ws;                      ws += (size_t)MM * DD * 2;
    unsigned short* kb  = (unsigned short*)ws;                      ws += (size_t)MM * DD * 2;
    unsigned short* vb  = (unsigned short*)ws;                      ws += (size_t)MM * DD * 2;
    unsigned short* yb  = (unsigned short*)ws;                      ws += (size_t)MM * DD * 2;
    float*          beta   = (float*)ws;                            ws += (size_t)MM * HH * 4;

    prep_all<<<6208, 256, 0, stream>>>(x, xb, Wb, Wbt, Wq, Wk, Wv, Wo, Wqt, Wkt, Wvt, Wot);
    gemm_qkv_beta<<<400, 256, 0, stream>>>(xb, Wqt, Wkt, Wvt, Wbt, bbp, qb, kb, vb, beta);
    scan_kernel<<<BB * HH, 256, 0, stream>>>(qb, kb, vb, beta, yb);
    gemm_out<<<32 * 8, 256, 0, stream>>>(yb, Wot, out);
}

// Round 6
// 145.892 us; speedup vs baseline: 1.1927x; 1.1927x over previous
//
#include <hip/hip_runtime.h>
#include <math.h>

#define BB   2
#define LL   1024
#define DD   1024
#define HH   16
#define HDIM 64
#define MM   (BB * LL)     // 2048
#define CHK  64            // chunk length
#define NCHK (LL / CHK)    // 16

typedef short bf16x8 __attribute__((ext_vector_type(8)));
typedef float f32x4  __attribute__((ext_vector_type(4)));
typedef const __attribute__((address_space(1))) unsigned int* gas_ptr;
typedef __attribute__((address_space(3))) unsigned int* las_ptr;

__device__ __forceinline__ void gload16(const void* g, void* l) {
    __builtin_amdgcn_global_load_lds((gas_ptr)(unsigned long long)g,
                                     (las_ptr)(unsigned long long)l, 16, 0, 0);
}

__device__ __forceinline__ unsigned short f2bf(float f) {
    unsigned int u = __float_as_uint(f);
    u += 0x7fffu + ((u >> 16) & 1u);      // RNE
    return (unsigned short)(u >> 16);
}
__device__ __forceinline__ float bfhi(unsigned int u) { return __uint_as_float(u & 0xffff0000u); }
__device__ __forceinline__ float bflo(unsigned int u) { return __uint_as_float(u << 16); }

// 8 bf16 from a [64][70]-strided LDS tile at [row][tc..tc+7]; 4-aligned -> 4x b32
__device__ __forceinline__ bf16x8 frag70(const unsigned short* a, int row, int tc) {
    const unsigned int* p = (const unsigned int*)(a + row * 70 + tc);
    union { unsigned int u[4]; bf16x8 v; } r;
    r.u[0] = p[0]; r.u[1] = p[1]; r.u[2] = p[2]; r.u[3] = p[3];
    return r.v;
}

// ---------------------------------------------------------------------------
// prep_all: [0,2048) x cast fp32->bf16; [2048,2112) Wb -> Wbt bf16 [h][k];
// [2112,6208) transpose+cast Wq/Wk/Wv/Wo fp32 [k][n] -> bf16 [n][k].
// ---------------------------------------------------------------------------
__global__ void prep_all(const float* __restrict__ x, unsigned short* __restrict__ xb,
                         const float* __restrict__ Wb, unsigned short* __restrict__ Wbt,
                         const float* __restrict__ W0, const float* __restrict__ W1,
                         const float* __restrict__ W2, const float* __restrict__ W3,
                         unsigned short* __restrict__ T0, unsigned short* __restrict__ T1,
                         unsigned short* __restrict__ T2, unsigned short* __restrict__ T3) {
    const int bid = blockIdx.x;
    if (bid < 2048) {
        const int idx = bid * 256 + threadIdx.x;
        const float4 v = ((const float4*)x)[idx];
        ushort4 o;
        o.x = f2bf(v.x); o.y = f2bf(v.y); o.z = f2bf(v.z); o.w = f2bf(v.w);
        ((ushort4*)xb)[idx] = o;
        return;
    }
    if (bid < 2112) {
        const int t = (bid - 2048) * 256 + threadIdx.x;   // h-major [h][k]
        const int h = t >> 10, kidx = t & 1023;
        Wbt[t] = f2bf(Wb[kidx * HH + h]);
        return;
    }
    __shared__ float tile[32][33];
    const int b4 = bid - 2112;
    const int which = b4 >> 10;
    const int b = b4 & 1023;
    const int bk = b >> 5, bn = b & 31;
    const float* W = which == 0 ? W0 : which == 1 ? W1 : which == 2 ? W2 : W3;
    unsigned short* T = which == 0 ? T0 : which == 1 ? T1 : which == 2 ? T2 : T3;
    const int tx = threadIdx.x & 31, ty = threadIdx.x >> 5;
#pragma unroll
    for (int i = 0; i < 4; ++i)
        tile[ty + i * 8][tx] = W[(size_t)(bk * 32 + ty + i * 8) * DD + bn * 32 + tx];
    __syncthreads();
#pragma unroll
    for (int i = 0; i < 4; ++i)
        T[(size_t)(bn * 32 + ty + i * 8) * DD + bk * 32 + tx] = f2bf(tile[tx][ty + i * 8]);
}

// ---------------------------------------------------------------------------
// bf16 MFMA GEMM K-loop (m97 structure): 128x128 tile, BK=32, 256 thr.
// ---------------------------------------------------------------------------
__device__ __forceinline__ void gemm_kloop(const unsigned short* A, const unsigned short* Bt,
                                           unsigned short* As, unsigned short* Bs,
                                           int rowBase, int colBase, int K,
                                           f32x4 acc[4][4]) {
    const int tid = threadIdx.x;
    const int c0 = tid, c1 = tid + 256;
    const int ar0 = c0 >> 2, ak0 = (c0 & 3) << 3;
    const int ar1 = c1 >> 2, ak1 = (c1 & 3) << 3;
    const unsigned short* Ag0 = A + (size_t)(rowBase + ar0) * K + ak0;
    const unsigned short* Ag1 = A + (size_t)(rowBase + ar1) * K + ak1;
    const unsigned short* Bg0 = Bt + (size_t)(colBase + ar0) * K + ak0;
    const unsigned short* Bg1 = Bt + (size_t)(colBase + ar1) * K + ak1;
    unsigned short* Al0 = As + c0 * 8; unsigned short* Al1 = As + c1 * 8;
    unsigned short* Bl0 = Bs + c0 * 8; unsigned short* Bl1 = Bs + c1 * 8;
    const int lane = tid & 63, wv = tid >> 6;
    const int qr = wv >> 1, qc = wv & 1;
    const int fr = lane & 15;
    const int koff = (lane >> 4) << 3;
    int aoff[4], boff[4];
#pragma unroll
    for (int mi = 0; mi < 4; ++mi) aoff[mi] = (qr * 64 + mi * 16 + fr) * 32 + koff;
#pragma unroll
    for (int nj = 0; nj < 4; ++nj) boff[nj] = (qc * 64 + nj * 16 + fr) * 32 + koff;

    for (int k0 = 0; k0 < K; k0 += 32) {
        __syncthreads();
        gload16(Ag0, Al0); gload16(Ag1, Al1);
        gload16(Bg0, Bl0); gload16(Bg1, Bl1);
        Ag0 += 32; Ag1 += 32; Bg0 += 32; Bg1 += 32;
        __syncthreads();
        bf16x8 av[4], bv[4];
#pragma unroll
        for (int mi = 0; mi < 4; ++mi) av[mi] = *(const bf16x8*)(As + aoff[mi]);
#pragma unroll
        for (int nj = 0; nj < 4; ++nj) bv[nj] = *(const bf16x8*)(Bs + boff[nj]);
#pragma unroll
        for (int mi = 0; mi < 4; ++mi)
#pragma unroll
            for (int nj = 0; nj < 4; ++nj)
                acc[mi][nj] = __builtin_amdgcn_mfma_f32_16x16x32_bf16(av[mi], bv[nj], acc[mi][nj], 0, 0, 0);
    }
}

// ---------------------------------------------------------------------------
// Fused q/k/v projection GEMM (+L2-norm epilogue for q,k) AND beta mini-GEMM.
// blocks [0,384): qkv; blocks [384,400): beta = sigmoid(x@Wb+bb).
// ---------------------------------------------------------------------------
__global__ __launch_bounds__(256) void gemm_qkv_beta(const unsigned short* __restrict__ xb,
                                                     const unsigned short* __restrict__ Wqt,
                                                     const unsigned short* __restrict__ Wkt,
                                                     const unsigned short* __restrict__ Wvt,
                                                     const unsigned short* __restrict__ Wbt,
                                                     const float* __restrict__ bbp,
                                                     unsigned short* __restrict__ qb,
                                                     unsigned short* __restrict__ kb,
                                                     unsigned short* __restrict__ vb,
                                                     float* __restrict__ beta) {
    __shared__ unsigned short As[128 * 32];
    __shared__ unsigned short Bs[128 * 32];
    const int lane = threadIdx.x & 63, wv = threadIdx.x >> 6;
    const int fr = lane & 15, quad = lane >> 4;
    if (blockIdx.x >= 384) {
        // ---- beta path: 16 blocks, 128 rows each, pure-register MFMA ----
        const int rowBase = (blockIdx.x - 384) * 128;
        const int r0 = rowBase + wv * 32 + fr;
        f32x4 bacc[2];
        bacc[0] = (f32x4){0.f, 0.f, 0.f, 0.f};
        bacc[1] = (f32x4){0.f, 0.f, 0.f, 0.f};
        for (int k0 = 0; k0 < DD; k0 += 32) {
            const int kk = k0 + quad * 8;
            const bf16x8 a0 = *(const bf16x8*)&xb[(size_t)r0 * DD + kk];
            const bf16x8 a1 = *(const bf16x8*)&xb[(size_t)(r0 + 16) * DD + kk];
            const bf16x8 bw = *(const bf16x8*)&Wbt[(size_t)fr * DD + kk];
            bacc[0] = __builtin_amdgcn_mfma_f32_16x16x32_bf16(a0, bw, bacc[0], 0, 0, 0);
            bacc[1] = __builtin_amdgcn_mfma_f32_16x16x32_bf16(a1, bw, bacc[1], 0, 0, 0);
        }
        const float bias = bbp[fr];
#pragma unroll
        for (int mi = 0; mi < 2; ++mi)
#pragma unroll
            for (int i = 0; i < 4; ++i) {
                const int row = rowBase + wv * 32 + mi * 16 + quad * 4 + i;
                const float s = bacc[mi][i] + bias;
                beta[row * HH + fr] = 1.0f / (1.0f + expf(-s));
            }
        return;
    }
    // ---- qkv path ----
    const int by = blockIdx.x / 24, bxx = blockIdx.x % 24;
    const int mat = bxx >> 3, tn = bxx & 7;
    const unsigned short* Bt = mat == 0 ? Wqt : (mat == 1 ? Wkt : Wvt);
    unsigned short* Cout = mat == 0 ? qb : (mat == 1 ? kb : vb);
    f32x4 acc[4][4];
#pragma unroll
    for (int mi = 0; mi < 4; ++mi)
#pragma unroll
        for (int nj = 0; nj < 4; ++nj) acc[mi][nj] = (f32x4){0.f, 0.f, 0.f, 0.f};
    gemm_kloop(xb, Bt, As, Bs, by * 128, tn * 128, DD, acc);

    const int qr = wv >> 1, qc = wv & 1;
    if (mat < 2) {
#pragma unroll
        for (int mi = 0; mi < 4; ++mi)
#pragma unroll
            for (int i = 0; i < 4; ++i) {
                float s = 0.f;
#pragma unroll
                for (int nj = 0; nj < 4; ++nj) { float t = acc[mi][nj][i]; s += t * t; }
                s += __shfl_xor(s, 1, 64);
                s += __shfl_xor(s, 2, 64);
                s += __shfl_xor(s, 4, 64);
                s += __shfl_xor(s, 8, 64);
                const float inv = 1.0f / fmaxf(sqrtf(s), 1e-12f);
#pragma unroll
                for (int nj = 0; nj < 4; ++nj) acc[mi][nj][i] *= inv;
            }
    }
#pragma unroll
    for (int mi = 0; mi < 4; ++mi)
#pragma unroll
        for (int i = 0; i < 4; ++i) {
            const int row = by * 128 + qr * 64 + mi * 16 + quad * 4 + i;
#pragma unroll
            for (int nj = 0; nj < 4; ++nj) {
                const int col = tn * 128 + qc * 64 + nj * 16 + fr;
                Cout[(size_t)row * DD + col] = f2bf(acc[mi][nj][i]);
            }
        }
}

// ---------------------------------------------------------------------------
// Per-chunk KV sums via MFMA: states[bh][c][d][e] = sum_t (beta*k)[t][d]*v[t][e]
// A = (beta*k)^T [d][t], B = v^T [e][t], both bf16 LDS stride-70. 512 blocks.
// ---------------------------------------------------------------------------
__global__ __launch_bounds__(256) void chunkkv_kernel(const unsigned short* __restrict__ k,
                                                      const unsigned short* __restrict__ v,
                                                      const float* __restrict__ beta,
                                                      float* __restrict__ states) {
    const int c = blockIdx.x % NCHK;
    const int bh = blockIdx.x / NCHK;
    const int b = bh / HH, h = bh % HH;
    __shared__ unsigned short kT[64 * 70];
    __shared__ unsigned short vT[64 * 70];
    const int tid = threadIdx.x;
    for (int i = tid; i < 512; i += 256) {
        const int t = i >> 3, dg = (i & 7) << 3;
        const int m = b * LL + c * CHK + t;
        const float be = beta[m * HH + h];
        const size_t go = (size_t)m * DD + h * 64 + dg;
        const uint4 ku = *(const uint4*)&k[go];
        const uint4 vu = *(const uint4*)&v[go];
        unsigned int kw[4] = {ku.x, ku.y, ku.z, ku.w};
        unsigned int vw[4] = {vu.x, vu.y, vu.z, vu.w};
#pragma unroll
        for (int jj = 0; jj < 4; ++jj) {
            kT[(dg + 2 * jj)     * 70 + t] = f2bf(bflo(kw[jj]) * be);
            kT[(dg + 2 * jj + 1) * 70 + t] = f2bf(bfhi(kw[jj]) * be);
            vT[(dg + 2 * jj)     * 70 + t] = (unsigned short)(vw[jj] & 0xffffu);
            vT[(dg + 2 * jj + 1) * 70 + t] = (unsigned short)(vw[jj] >> 16);
        }
    }
    __syncthreads();
    const int lane = tid & 63, wv = tid >> 6;
    const int fr = lane & 15, quad = lane >> 4;
    f32x4 acc[4];
#pragma unroll
    for (int et = 0; et < 4; ++et) acc[et] = (f32x4){0.f, 0.f, 0.f, 0.f};
#pragma unroll
    for (int kh = 0; kh < 2; ++kh) {
        const int tc = kh * 32 + quad * 8;
        const bf16x8 a = frag70(kT, wv * 16 + fr, tc);
#pragma unroll
        for (int et = 0; et < 4; ++et) {
            const bf16x8 bb = frag70(vT, et * 16 + fr, tc);
            acc[et] = __builtin_amdgcn_mfma_f32_16x16x32_bf16(a, bb, acc[et], 0, 0, 0);
        }
    }
    float* outp = states + ((size_t)bh * NCHK + c) * 4096;
#pragma unroll
    for (int et = 0; et < 4; ++et)
#pragma unroll
        for (int i = 0; i < 4; ++i) {
            const int d = wv * 16 + quad * 4 + i;
            const int e = et * 16 + fr;
            outp[d * 64 + e] = acc[et][i];
        }
}

// ---------------------------------------------------------------------------
// Per-chunk output via MFMA with inline prefix: block (bh,c) sums raw states
// of chunks 0..c-1 in registers (no separate prefix kernel).
// S = q@k^T (masked) -> P bf16; O = P@(beta*v) + q@st -> y bf16.  512 blocks.
// ---------------------------------------------------------------------------
__global__ __launch_bounds__(256) void attn_kernel(const unsigned short* __restrict__ q,
                                                   const unsigned short* __restrict__ k,
                                                   const unsigned short* __restrict__ v,
                                                   const float* __restrict__ beta,
                                                   const float* __restrict__ states,
                                                   unsigned short* __restrict__ y) {
    const int c = blockIdx.x % NCHK;
    const int bh = blockIdx.x / NCHK;
    const int b = bh / HH, h = bh % HH;
    __shared__ unsigned short qS[64 * 80];   // [t][d], stride 80 (16B-aligned rows)
    __shared__ unsigned short kS[64 * 80];   // [s][d]
    __shared__ unsigned short sS[64 * 80];   // masked P [t][s]
    __shared__ unsigned short vT[64 * 70];   // (beta*v)^T [e][s]
    __shared__ unsigned short sT[64 * 70];   // prefix-state^T [e][d]
    const int tid = threadIdx.x;
    for (int i = tid; i < 512; i += 256) {
        const int t = i >> 3, dg = (i & 7) << 3;
        const int m = b * LL + c * CHK + t;
        const float be = beta[m * HH + h];
        const size_t go = (size_t)m * DD + h * 64 + dg;
        const uint4 qu = *(const uint4*)&q[go];
        const uint4 ku = *(const uint4*)&k[go];
        const uint4 vu = *(const uint4*)&v[go];
        *(uint4*)&qS[t * 80 + dg] = qu;
        *(uint4*)&kS[t * 80 + dg] = ku;
        unsigned int vw[4] = {vu.x, vu.y, vu.z, vu.w};
#pragma unroll
        for (int jj = 0; jj < 4; ++jj) {
            vT[(dg + 2 * jj)     * 70 + t] = f2bf(bflo(vw[jj]) * be);
            vT[(dg + 2 * jj + 1) * 70 + t] = f2bf(bfhi(vw[jj]) * be);
        }
    }
    // inline exclusive prefix: sum raw chunk states 0..c-1 (ascending, matches
    // the R4/R5 summation order -> identical numerics), then transpose to sT.
    {
        float racc[16];
#pragma unroll
        for (int j = 0; j < 16; ++j) racc[j] = 0.f;
        const float* sbase = states + (size_t)bh * NCHK * 4096;
        for (int cc = 0; cc < c; ++cc) {
            const float* sp = sbase + cc * 4096;
#pragma unroll
            for (int j = 0; j < 16; ++j) racc[j] += sp[j * 256 + tid];
        }
        const int e = tid & 63;          // p & 63   (p = j*256 + tid)
        const int dbase = tid >> 6;      // p >> 6 = j*4 + (tid>>6)
#pragma unroll
        for (int j = 0; j < 16; ++j)
            sT[e * 70 + j * 4 + dbase] = f2bf(racc[j]);
    }
    __syncthreads();
    const int lane = tid & 63, wv = tid >> 6;
    const int fr = lane & 15, quad = lane >> 4;
    const int koff = quad * 8;
    // phase 1: S row-tile wv (rows wv*16..+15), all 4 col-tiles
    f32x4 s_acc[4];
#pragma unroll
    for (int j = 0; j < 4; ++j) s_acc[j] = (f32x4){0.f, 0.f, 0.f, 0.f};
#pragma unroll
    for (int kh = 0; kh < 2; ++kh) {
        const bf16x8 a = *(const bf16x8*)&qS[(wv * 16 + fr) * 80 + kh * 32 + koff];
#pragma unroll
        for (int j = 0; j < 4; ++j) {
            const bf16x8 bb = *(const bf16x8*)&kS[(j * 16 + fr) * 80 + kh * 32 + koff];
            s_acc[j] = __builtin_amdgcn_mfma_f32_16x16x32_bf16(a, bb, s_acc[j], 0, 0, 0);
        }
    }
    // mask + store P (bf16). Rows written == rows this wave reads below: no barrier.
#pragma unroll
    for (int j = 0; j < 4; ++j)
#pragma unroll
        for (int i = 0; i < 4; ++i) {
            const int t = wv * 16 + quad * 4 + i;
            const int s = j * 16 + fr;
            sS[t * 80 + s] = (s <= t) ? f2bf(s_acc[j][i]) : (unsigned short)0;
        }
    // phase 2: O = P@vT + q@sT
    f32x4 o_acc[4];
#pragma unroll
    for (int j = 0; j < 4; ++j) o_acc[j] = (f32x4){0.f, 0.f, 0.f, 0.f};
#pragma unroll
    for (int kh = 0; kh < 2; ++kh) {
        const bf16x8 a = *(const bf16x8*)&sS[(wv * 16 + fr) * 80 + kh * 32 + koff];
#pragma unroll
        for (int j = 0; j < 4; ++j) {
            const bf16x8 bb = frag70(vT, j * 16 + fr, kh * 32 + koff);
            o_acc[j] = __builtin_amdgcn_mfma_f32_16x16x32_bf16(a, bb, o_acc[j], 0, 0, 0);
        }
    }
#pragma unroll
    for (int kh = 0; kh < 2; ++kh) {
        const bf16x8 a = *(const bf16x8*)&qS[(wv * 16 + fr) * 80 + kh * 32 + koff];
#pragma unroll
        for (int j = 0; j < 4; ++j) {
            const bf16x8 bb = frag70(sT, j * 16 + fr, kh * 32 + koff);
            o_acc[j] = __builtin_amdgcn_mfma_f32_16x16x32_bf16(a, bb, o_acc[j], 0, 0, 0);
        }
    }
#pragma unroll
    for (int j = 0; j < 4; ++j)
#pragma unroll
        for (int i = 0; i < 4; ++i) {
            const int m = b * LL + c * CHK + wv * 16 + quad * 4 + i;
            const int e = j * 16 + fr;
            y[(size_t)m * DD + h * 64 + e] = f2bf(o_acc[j][i]);
        }
}

// ---------------------------------------------------------------------------
// Output GEMM: out = y(bf16) @ Wo -> fp32. 64x128 tile, grid = 32*8 = 256.
// ---------------------------------------------------------------------------
__global__ __launch_bounds__(256) void gemm_out(const unsigned short* __restrict__ yb,
                                                const unsigned short* __restrict__ Wot,
                                                float* __restrict__ out) {
    __shared__ unsigned short As[64 * 32];
    __shared__ unsigned short Bs[128 * 32];
    const int by = blockIdx.x >> 3, tn = blockIdx.x & 7;
    const int tid = threadIdx.x;
    const int rowBase = by * 64, colBase = tn * 128;
    const int ar = tid >> 2, ak = (tid & 3) << 3;
    const unsigned short* Ag = yb + (size_t)(rowBase + ar) * DD + ak;
    unsigned short* Al = As + tid * 8;
    const int c1 = tid + 256;
    const int br1 = c1 >> 2, bk1 = (c1 & 3) << 3;
    const unsigned short* Bg0 = Wot + (size_t)(colBase + ar) * DD + ak;
    const unsigned short* Bg1 = Wot + (size_t)(colBase + br1) * DD + bk1;
    unsigned short* Bl0 = Bs + tid * 8; unsigned short* Bl1 = Bs + c1 * 8;
    const int lane = tid & 63, wv = tid >> 6;
    const int rh = wv & 1, ch = wv >> 1;
    const int fr = lane & 15, koff = (lane >> 4) << 3;
    int aoff[2], boff[4];
#pragma unroll
    for (int mi = 0; mi < 2; ++mi) aoff[mi] = (rh * 32 + mi * 16 + fr) * 32 + koff;
#pragma unroll
    for (int nj = 0; nj < 4; ++nj) boff[nj] = (ch * 64 + nj * 16 + fr) * 32 + koff;
    f32x4 acc[2][4];
#pragma unroll
    for (int mi = 0; mi < 2; ++mi)
#pragma unroll
        for (int nj = 0; nj < 4; ++nj) acc[mi][nj] = (f32x4){0.f, 0.f, 0.f, 0.f};
    for (int k0 = 0; k0 < DD; k0 += 32) {
        __syncthreads();
        gload16(Ag, Al); gload16(Bg0, Bl0); gload16(Bg1, Bl1);
        Ag += 32; Bg0 += 32; Bg1 += 32;
        __syncthreads();
        bf16x8 av[2], bv[4];
#pragma unroll
        for (int mi = 0; mi < 2; ++mi) av[mi] = *(const bf16x8*)(As + aoff[mi]);
#pragma unroll
        for (int nj = 0; nj < 4; ++nj) bv[nj] = *(const bf16x8*)(Bs + boff[nj]);
#pragma unroll
        for (int mi = 0; mi < 2; ++mi)
#pragma unroll
            for (int nj = 0; nj < 4; ++nj)
                acc[mi][nj] = __builtin_amdgcn_mfma_f32_16x16x32_bf16(av[mi], bv[nj], acc[mi][nj], 0, 0, 0);
    }
    const int quad = lane >> 4;
#pragma unroll
    for (int mi = 0; mi < 2; ++mi)
#pragma unroll
        for (int i = 0; i < 4; ++i) {
            const int row = rowBase + rh * 32 + mi * 16 + quad * 4 + i;
#pragma unroll
            for (int nj = 0; nj < 4; ++nj) {
                const int col = colBase + ch * 64 + nj * 16 + fr;
                out[(size_t)row * DD + col] = acc[mi][nj][i];
            }
        }
}

// ---------------------------------------------------------------------------
extern "C" void kernel_launch(void* const* d_in, const int* in_sizes, int n_in,
                              void* d_out, int out_size, void* d_ws, size_t ws_size,
                              hipStream_t stream) {
    (void)in_sizes; (void)n_in; (void)out_size; (void)ws_size;
    const float* x  = (const float*)d_in[0];
    const float* Wq = (const float*)d_in[1];
    const float* Wk = (const float*)d_in[2];
    const float* Wv = (const float*)d_in[3];
    const float* Wo = (const float*)d_in[4];
    const float* Wb = (const float*)d_in[5];
    const float* bbp = (const float*)d_in[6];
    float* out = (float*)d_out;

    char* ws = (char*)d_ws;
    unsigned short* xb  = (unsigned short*)ws;                      ws += (size_t)MM * DD * 2;
    unsigned short* Wqt = (unsigned short*)ws;                      ws += (size_t)DD * DD * 2;
    unsigned short* Wkt = (unsigned short*)ws;                      ws += (size_t)DD * DD * 2;
    unsigned short* Wvt = (unsigned short*)ws;                      ws += (size_t)DD * DD * 2;
    unsigned short* Wot = (unsigned short*)ws;                      ws += (size_t)DD * DD * 2;
    unsigned short* Wbt = (unsigned short*)ws;                      ws += (size_t)HH * DD * 2;
    unsigned short* qb  = (unsigned short*)ws;                      ws += (size_t)MM * DD * 2;
    unsigned short* kb  = (unsigned short*)ws;                      ws += (size_t)MM * DD * 2;
    unsigned short* vb  = (unsigned short*)ws;                      ws += (size_t)MM * DD * 2;
    unsigned short* yb  = (unsigned short*)ws;                      ws += (size_t)MM * DD * 2;
    float*          beta   = (float*)ws;                            ws += (size_t)MM * HH * 4;
    float*          states = (float*)ws;                            ws += (size_t)BB * HH * NCHK * 4096 * 4;

    prep_all<<<6208, 256, 0, stream>>>(x, xb, Wb, Wbt, Wq, Wk, Wv, Wo, Wqt, Wkt, Wvt, Wot);
    gemm_qkv_beta<<<400, 256, 0, stream>>>(xb, Wqt, Wkt, Wvt, Wbt, bbp, qb, kb, vb, beta);
    chunkkv_kernel<<<BB * HH * NCHK, 256, 0, stream>>>(kb, vb, beta, states);
    attn_kernel<<<BB * HH * NCHK, 256, 0, stream>>>(qb, kb, vb, beta, states, yb);
    gemm_out<<<32 * 8, 256, 0, stream>>>(yb, Wot, out);
}

// Round 7
// 134.034 us; speedup vs baseline: 1.2982x; 1.0885x over previous
//
#include <hip/hip_runtime.h>
#include <math.h>

#define BB   2
#define LL   1024
#define DD   1024
#define HH   16
#define HDIM 64
#define MM   (BB * LL)     // 2048
#define CHK  64            // chunk length
#define NCHK (LL / CHK)    // 16

typedef short bf16x8 __attribute__((ext_vector_type(8)));
typedef float f32x4  __attribute__((ext_vector_type(4)));
typedef const __attribute__((address_space(1))) unsigned int* gas_ptr;
typedef __attribute__((address_space(3))) unsigned int* las_ptr;

__device__ __forceinline__ void gload16(const void* g, void* l) {
    __builtin_amdgcn_global_load_lds((gas_ptr)(unsigned long long)g,
                                     (las_ptr)(unsigned long long)l, 16, 0, 0);
}

__device__ __forceinline__ unsigned short f2bf(float f) {
    unsigned int u = __float_as_uint(f);
    u += 0x7fffu + ((u >> 16) & 1u);      // RNE
    return (unsigned short)(u >> 16);
}
__device__ __forceinline__ float bfhi(unsigned int u) { return __uint_as_float(u & 0xffff0000u); }
__device__ __forceinline__ float bflo(unsigned int u) { return __uint_as_float(u << 16); }

// ---------------------------------------------------------------------------
// prep_all: [0,2048) x cast fp32->bf16; [2048,2112) Wb -> Wbt bf16 [h][k];
// [2112,6208) transpose+cast Wq/Wk/Wv/Wo fp32 [k][n] -> bf16 [n][k].
// ---------------------------------------------------------------------------
__global__ void prep_all(const float* __restrict__ x, unsigned short* __restrict__ xb,
                         const float* __restrict__ Wb, unsigned short* __restrict__ Wbt,
                         const float* __restrict__ W0, const float* __restrict__ W1,
                         const float* __restrict__ W2, const float* __restrict__ W3,
                         unsigned short* __restrict__ T0, unsigned short* __restrict__ T1,
                         unsigned short* __restrict__ T2, unsigned short* __restrict__ T3) {
    const int bid = blockIdx.x;
    if (bid < 2048) {
        const int idx = bid * 256 + threadIdx.x;
        const float4 v = ((const float4*)x)[idx];
        ushort4 o;
        o.x = f2bf(v.x); o.y = f2bf(v.y); o.z = f2bf(v.z); o.w = f2bf(v.w);
        ((ushort4*)xb)[idx] = o;
        return;
    }
    if (bid < 2112) {
        const int t = (bid - 2048) * 256 + threadIdx.x;   // h-major [h][k]
        const int h = t >> 10, kidx = t & 1023;
        Wbt[t] = f2bf(Wb[kidx * HH + h]);
        return;
    }
    __shared__ float tile[32][33];
    const int b4 = bid - 2112;
    const int which = b4 >> 10;
    const int b = b4 & 1023;
    const int bk = b >> 5, bn = b & 31;
    const float* W = which == 0 ? W0 : which == 1 ? W1 : which == 2 ? W2 : W3;
    unsigned short* T = which == 0 ? T0 : which == 1 ? T1 : which == 2 ? T2 : T3;
    const int tx = threadIdx.x & 31, ty = threadIdx.x >> 5;
#pragma unroll
    for (int i = 0; i < 4; ++i)
        tile[ty + i * 8][tx] = W[(size_t)(bk * 32 + ty + i * 8) * DD + bn * 32 + tx];
    __syncthreads();
#pragma unroll
    for (int i = 0; i < 4; ++i)
        T[(size_t)(bn * 32 + ty + i * 8) * DD + bk * 32 + tx] = f2bf(tile[tx][ty + i * 8]);
}

// ---------------------------------------------------------------------------
// bf16 MFMA GEMM K-loop, double-buffered LDS: 128x128 tile, BK=32, 256 thr.
// One barrier per K-iter; prefetch of iter k+1 issued right after the barrier
// so the compiler's vmcnt(0)-before-barrier drain is overlapped by compute.
// As/Bs are 2x4096 shorts (double buffers).
// ---------------------------------------------------------------------------
__device__ __forceinline__ void gemm_kloop_db(const unsigned short* A, const unsigned short* Bt,
                                              unsigned short* As, unsigned short* Bs,
                                              int rowBase, int colBase, int K,
                                              f32x4 acc[4][4]) {
    const int tid = threadIdx.x;
    const int c0 = tid, c1 = tid + 256;
    const int ar0 = c0 >> 2, ak0 = (c0 & 3) << 3;
    const int ar1 = c1 >> 2, ak1 = (c1 & 3) << 3;
    const unsigned short* Ag0 = A + (size_t)(rowBase + ar0) * K + ak0;
    const unsigned short* Ag1 = A + (size_t)(rowBase + ar1) * K + ak1;
    const unsigned short* Bg0 = Bt + (size_t)(colBase + ar0) * K + ak0;
    const unsigned short* Bg1 = Bt + (size_t)(colBase + ar1) * K + ak1;
    const int lane = tid & 63, wv = tid >> 6;
    const int qr = wv >> 1, qc = wv & 1;
    const int fr = lane & 15;
    const int koff = (lane >> 4) << 3;
    int aoff[4], boff[4];
#pragma unroll
    for (int mi = 0; mi < 4; ++mi) aoff[mi] = (qr * 64 + mi * 16 + fr) * 32 + koff;
#pragma unroll
    for (int nj = 0; nj < 4; ++nj) boff[nj] = (qc * 64 + nj * 16 + fr) * 32 + koff;

    // prologue: stage buffer 0
    gload16(Ag0, As + c0 * 8); gload16(Ag1, As + c1 * 8);
    gload16(Bg0, Bs + c0 * 8); gload16(Bg1, Bs + c1 * 8);
    Ag0 += 32; Ag1 += 32; Bg0 += 32; Bg1 += 32;

    for (int k0 = 0; k0 < K; k0 += 32) {
        const int cur = (k0 >> 5) & 1;
        const int nxt = cur ^ 1;
        __syncthreads();   // cur's loads drained; nxt's readers (prev iter) done
        if (k0 + 32 < K) {
            gload16(Ag0, As + nxt * 4096 + c0 * 8); gload16(Ag1, As + nxt * 4096 + c1 * 8);
            gload16(Bg0, Bs + nxt * 4096 + c0 * 8); gload16(Bg1, Bs + nxt * 4096 + c1 * 8);
            Ag0 += 32; Ag1 += 32; Bg0 += 32; Bg1 += 32;
        }
        const unsigned short* Ab = As + cur * 4096;
        const unsigned short* Bb = Bs + cur * 4096;
        bf16x8 av[4], bv[4];
#pragma unroll
        for (int mi = 0; mi < 4; ++mi) av[mi] = *(const bf16x8*)(Ab + aoff[mi]);
#pragma unroll
        for (int nj = 0; nj < 4; ++nj) bv[nj] = *(const bf16x8*)(Bb + boff[nj]);
#pragma unroll
        for (int mi = 0; mi < 4; ++mi)
#pragma unroll
            for (int nj = 0; nj < 4; ++nj)
                acc[mi][nj] = __builtin_amdgcn_mfma_f32_16x16x32_bf16(av[mi], bv[nj], acc[mi][nj], 0, 0, 0);
    }
}

// ---------------------------------------------------------------------------
// Fused q/k/v projection GEMM (+L2-norm epilogue for q,k) AND beta mini-GEMM.
// blocks [0,384): qkv; blocks [384,400): beta = sigmoid(x@Wb+bb).
// ---------------------------------------------------------------------------
__global__ __launch_bounds__(256) void gemm_qkv_beta(const unsigned short* __restrict__ xb,
                                                     const unsigned short* __restrict__ Wqt,
                                                     const unsigned short* __restrict__ Wkt,
                                                     const unsigned short* __restrict__ Wvt,
                                                     const unsigned short* __restrict__ Wbt,
                                                     const float* __restrict__ bbp,
                                                     unsigned short* __restrict__ qb,
                                                     unsigned short* __restrict__ kb,
                                                     unsigned short* __restrict__ vb,
                                                     float* __restrict__ beta) {
    __shared__ unsigned short As[2 * 128 * 32];
    __shared__ unsigned short Bs[2 * 128 * 32];
    const int lane = threadIdx.x & 63, wv = threadIdx.x >> 6;
    const int fr = lane & 15, quad = lane >> 4;
    if (blockIdx.x >= 384) {
        // ---- beta path: 16 blocks, 128 rows each, pure-register MFMA ----
        const int rowBase = (blockIdx.x - 384) * 128;
        const int r0 = rowBase + wv * 32 + fr;
        f32x4 bacc[2];
        bacc[0] = (f32x4){0.f, 0.f, 0.f, 0.f};
        bacc[1] = (f32x4){0.f, 0.f, 0.f, 0.f};
        for (int k0 = 0; k0 < DD; k0 += 32) {
            const int kk = k0 + quad * 8;
            const bf16x8 a0 = *(const bf16x8*)&xb[(size_t)r0 * DD + kk];
            const bf16x8 a1 = *(const bf16x8*)&xb[(size_t)(r0 + 16) * DD + kk];
            const bf16x8 bw = *(const bf16x8*)&Wbt[(size_t)fr * DD + kk];
            bacc[0] = __builtin_amdgcn_mfma_f32_16x16x32_bf16(a0, bw, bacc[0], 0, 0, 0);
            bacc[1] = __builtin_amdgcn_mfma_f32_16x16x32_bf16(a1, bw, bacc[1], 0, 0, 0);
        }
        const float bias = bbp[fr];
#pragma unroll
        for (int mi = 0; mi < 2; ++mi)
#pragma unroll
            for (int i = 0; i < 4; ++i) {
                const int row = rowBase + wv * 32 + mi * 16 + quad * 4 + i;
                const float s = bacc[mi][i] + bias;
                beta[row * HH + fr] = 1.0f / (1.0f + expf(-s));
            }
        return;
    }
    // ---- qkv path ----
    const int by = blockIdx.x / 24, bxx = blockIdx.x % 24;
    const int mat = bxx >> 3, tn = bxx & 7;
    const unsigned short* Bt = mat == 0 ? Wqt : (mat == 1 ? Wkt : Wvt);
    unsigned short* Cout = mat == 0 ? qb : (mat == 1 ? kb : vb);
    f32x4 acc[4][4];
#pragma unroll
    for (int mi = 0; mi < 4; ++mi)
#pragma unroll
        for (int nj = 0; nj < 4; ++nj) acc[mi][nj] = (f32x4){0.f, 0.f, 0.f, 0.f};
    gemm_kloop_db(xb, Bt, As, Bs, by * 128, tn * 128, DD, acc);

    const int qr = wv >> 1, qc = wv & 1;
    if (mat < 2) {
#pragma unroll
        for (int mi = 0; mi < 4; ++mi)
#pragma unroll
            for (int i = 0; i < 4; ++i) {
                float s = 0.f;
#pragma unroll
                for (int nj = 0; nj < 4; ++nj) { float t = acc[mi][nj][i]; s += t * t; }
                s += __shfl_xor(s, 1, 64);
                s += __shfl_xor(s, 2, 64);
                s += __shfl_xor(s, 4, 64);
                s += __shfl_xor(s, 8, 64);
                const float inv = 1.0f / fmaxf(sqrtf(s), 1e-12f);
#pragma unroll
                for (int nj = 0; nj < 4; ++nj) acc[mi][nj][i] *= inv;
            }
    }
#pragma unroll
    for (int mi = 0; mi < 4; ++mi)
#pragma unroll
        for (int i = 0; i < 4; ++i) {
            const int row = by * 128 + qr * 64 + mi * 16 + quad * 4 + i;
#pragma unroll
            for (int nj = 0; nj < 4; ++nj) {
                const int col = tn * 128 + qc * 64 + nj * 16 + fr;
                Cout[(size_t)row * DD + col] = f2bf(acc[mi][nj][i]);
            }
        }
}

// ---------------------------------------------------------------------------
// Per-chunk KV sums via MFMA: state[d][e] = sum_t (beta*k)[t][d]*v[t][e].
// Output stored bf16, TRANSPOSED [e][d] (coalesced via LDS round-trip), so
// attn reads it directly into sT with no transpose. 512 blocks.
// ---------------------------------------------------------------------------
__global__ __launch_bounds__(256) void chunkkv_kernel(const unsigned short* __restrict__ k,
                                                      const unsigned short* __restrict__ v,
                                                      const float* __restrict__ beta,
                                                      unsigned short* __restrict__ states) {
    const int c = blockIdx.x % NCHK;
    const int bh = blockIdx.x / NCHK;
    const int b = bh / HH, h = bh % HH;
    __shared__ __align__(16) unsigned short kT[64 * 72];   // (beta*k)^T [d][t]
    __shared__ __align__(16) unsigned short vT[64 * 72];   // v^T [e][t]
    __shared__ __align__(16) unsigned short tT[64 * 72];   // result^T [e][d]
    const int tid = threadIdx.x;
    for (int i = tid; i < 512; i += 256) {
        const int t = i >> 3, dg = (i & 7) << 3;
        const int m = b * LL + c * CHK + t;
        const float be = beta[m * HH + h];
        const size_t go = (size_t)m * DD + h * 64 + dg;
        const uint4 ku = *(const uint4*)&k[go];
        const uint4 vu = *(const uint4*)&v[go];
        unsigned int kw[4] = {ku.x, ku.y, ku.z, ku.w};
        unsigned int vw[4] = {vu.x, vu.y, vu.z, vu.w};
#pragma unroll
        for (int jj = 0; jj < 4; ++jj) {
            kT[(dg + 2 * jj)     * 72 + t] = f2bf(bflo(kw[jj]) * be);
            kT[(dg + 2 * jj + 1) * 72 + t] = f2bf(bfhi(kw[jj]) * be);
            vT[(dg + 2 * jj)     * 72 + t] = (unsigned short)(vw[jj] & 0xffffu);
            vT[(dg + 2 * jj + 1) * 72 + t] = (unsigned short)(vw[jj] >> 16);
        }
    }
    __syncthreads();
    const int lane = tid & 63, wv = tid >> 6;
    const int fr = lane & 15, quad = lane >> 4;
    f32x4 acc[4];
#pragma unroll
    for (int et = 0; et < 4; ++et) acc[et] = (f32x4){0.f, 0.f, 0.f, 0.f};
#pragma unroll
    for (int kh = 0; kh < 2; ++kh) {
        const int tc = kh * 32 + quad * 8;
        const bf16x8 a = *(const bf16x8*)&kT[(wv * 16 + fr) * 72 + tc];
#pragma unroll
        for (int et = 0; et < 4; ++et) {
            const bf16x8 bb = *(const bf16x8*)&vT[(et * 16 + fr) * 72 + tc];
            acc[et] = __builtin_amdgcn_mfma_f32_16x16x32_bf16(a, bb, acc[et], 0, 0, 0);
        }
    }
    // transpose to [e][d] in LDS, then coalesced bf16 store
#pragma unroll
    for (int et = 0; et < 4; ++et)
#pragma unroll
        for (int i = 0; i < 4; ++i)
            tT[(et * 16 + fr) * 72 + wv * 16 + quad * 4 + i] = f2bf(acc[et][i]);
    __syncthreads();
    unsigned short* outp = states + ((size_t)bh * NCHK + c) * 4096;
#pragma unroll
    for (int s = 0; s < 2; ++s) {
        const int p = tid * 16 + s * 8;
        const int e = p >> 6, d = p & 63;
        *(uint4*)&outp[p] = *(const uint4*)&tT[e * 72 + d];
    }
}

// ---------------------------------------------------------------------------
// Per-chunk output via MFMA with inline prefix over bf16 [e][d] chunk states.
// S = q@k^T (masked) -> P bf16; O = P@(beta*v) + q@st -> y bf16.  512 blocks.
// ---------------------------------------------------------------------------
__global__ __launch_bounds__(256) void attn_kernel(const unsigned short* __restrict__ q,
                                                   const unsigned short* __restrict__ k,
                                                   const unsigned short* __restrict__ v,
                                                   const float* __restrict__ beta,
                                                   const unsigned short* __restrict__ states,
                                                   unsigned short* __restrict__ y) {
    const int c = blockIdx.x % NCHK;
    const int bh = blockIdx.x / NCHK;
    const int b = bh / HH, h = bh % HH;
    __shared__ __align__(16) unsigned short qS[64 * 80];   // [t][d]
    __shared__ __align__(16) unsigned short kS[64 * 80];   // [s][d]
    __shared__ __align__(16) unsigned short sS[64 * 80];   // masked P [t][s]
    __shared__ __align__(16) unsigned short vT[64 * 72];   // (beta*v)^T [e][s]
    __shared__ __align__(16) unsigned short sT[64 * 72];   // prefix-state [e][d]
    const int tid = threadIdx.x;
    for (int i = tid; i < 512; i += 256) {
        const int t = i >> 3, dg = (i & 7) << 3;
        const int m = b * LL + c * CHK + t;
        const float be = beta[m * HH + h];
        const size_t go = (size_t)m * DD + h * 64 + dg;
        const uint4 qu = *(const uint4*)&q[go];
        const uint4 ku = *(const uint4*)&k[go];
        const uint4 vu = *(const uint4*)&v[go];
        *(uint4*)&qS[t * 80 + dg] = qu;
        *(uint4*)&kS[t * 80 + dg] = ku;
        unsigned int vw[4] = {vu.x, vu.y, vu.z, vu.w};
#pragma unroll
        for (int jj = 0; jj < 4; ++jj) {
            vT[(dg + 2 * jj)     * 72 + t] = f2bf(bflo(vw[jj]) * be);
            vT[(dg + 2 * jj + 1) * 72 + t] = f2bf(bfhi(vw[jj]) * be);
        }
    }
    // inline exclusive prefix: fp32-accumulate bf16 chunk states 0..c-1
    {
        float racc[16];
#pragma unroll
        for (int j = 0; j < 16; ++j) racc[j] = 0.f;
        const unsigned short* sbase = states + (size_t)bh * NCHK * 4096;
        const int p0 = tid * 16;
        for (int cc = 0; cc < c; ++cc) {
            const uint4 u0 = *(const uint4*)&sbase[cc * 4096 + p0];
            const uint4 u1 = *(const uint4*)&sbase[cc * 4096 + p0 + 8];
            const unsigned int w[8] = {u0.x, u0.y, u0.z, u0.w, u1.x, u1.y, u1.z, u1.w};
#pragma unroll
            for (int j = 0; j < 8; ++j) {
                racc[2 * j]     += bflo(w[j]);
                racc[2 * j + 1] += bfhi(w[j]);
            }
        }
        const int e = p0 >> 6, d0 = p0 & 63;   // p0..p0+15 stay in row e
#pragma unroll
        for (int j = 0; j < 16; ++j)
            sT[e * 72 + d0 + j] = f2bf(racc[j]);
    }
    __syncthreads();
    const int lane = tid & 63, wv = tid >> 6;
    const int fr = lane & 15, quad = lane >> 4;
    const int koff = quad * 8;
    // phase 1: S row-tile wv, all 4 col-tiles
    f32x4 s_acc[4];
#pragma unroll
    for (int j = 0; j < 4; ++j) s_acc[j] = (f32x4){0.f, 0.f, 0.f, 0.f};
#pragma unroll
    for (int kh = 0; kh < 2; ++kh) {
        const bf16x8 a = *(const bf16x8*)&qS[(wv * 16 + fr) * 80 + kh * 32 + koff];
#pragma unroll
        for (int j = 0; j < 4; ++j) {
            const bf16x8 bb = *(const bf16x8*)&kS[(j * 16 + fr) * 80 + kh * 32 + koff];
            s_acc[j] = __builtin_amdgcn_mfma_f32_16x16x32_bf16(a, bb, s_acc[j], 0, 0, 0);
        }
    }
    // mask + store P (rows written == rows this wave reads: no barrier)
#pragma unroll
    for (int j = 0; j < 4; ++j)
#pragma unroll
        for (int i = 0; i < 4; ++i) {
            const int t = wv * 16 + quad * 4 + i;
            const int s = j * 16 + fr;
            sS[t * 80 + s] = (s <= t) ? f2bf(s_acc[j][i]) : (unsigned short)0;
        }
    // phase 2: O = P@vT + q@sT
    f32x4 o_acc[4];
#pragma unroll
    for (int j = 0; j < 4; ++j) o_acc[j] = (f32x4){0.f, 0.f, 0.f, 0.f};
#pragma unroll
    for (int kh = 0; kh < 2; ++kh) {
        const bf16x8 a = *(const bf16x8*)&sS[(wv * 16 + fr) * 80 + kh * 32 + koff];
#pragma unroll
        for (int j = 0; j < 4; ++j) {
            const bf16x8 bb = *(const bf16x8*)&vT[(j * 16 + fr) * 72 + kh * 32 + koff];
            o_acc[j] = __builtin_amdgcn_mfma_f32_16x16x32_bf16(a, bb, o_acc[j], 0, 0, 0);
        }
    }
#pragma unroll
    for (int kh = 0; kh < 2; ++kh) {
        const bf16x8 a = *(const bf16x8*)&qS[(wv * 16 + fr) * 80 + kh * 32 + koff];
#pragma unroll
        for (int j = 0; j < 4; ++j) {
            const bf16x8 bb = *(const bf16x8*)&sT[(j * 16 + fr) * 72 + kh * 32 + koff];
            o_acc[j] = __builtin_amdgcn_mfma_f32_16x16x32_bf16(a, bb, o_acc[j], 0, 0, 0);
        }
    }
#pragma unroll
    for (int j = 0; j < 4; ++j)
#pragma unroll
        for (int i = 0; i < 4; ++i) {
            const int m = b * LL + c * CHK + wv * 16 + quad * 4 + i;
            const int e = j * 16 + fr;
            y[(size_t)m * DD + h * 64 + e] = f2bf(o_acc[j][i]);
        }
}

// ---------------------------------------------------------------------------
// Output GEMM: out = y(bf16) @ Wo -> fp32. 64x128 tile, double-buffered LDS.
// grid = 32*8 = 256.
// ---------------------------------------------------------------------------
__global__ __launch_bounds__(256) void gemm_out(const unsigned short* __restrict__ yb,
                                                const unsigned short* __restrict__ Wot,
                                                float* __restrict__ out) {
    __shared__ unsigned short As[2 * 64 * 32];
    __shared__ unsigned short Bs[2 * 128 * 32];
    const int by = blockIdx.x >> 3, tn = blockIdx.x & 7;
    const int tid = threadIdx.x;
    const int rowBase = by * 64, colBase = tn * 128;
    const int ar = tid >> 2, ak = (tid & 3) << 3;
    const unsigned short* Ag = yb + (size_t)(rowBase + ar) * DD + ak;
    const int c1 = tid + 256;
    const int br1 = c1 >> 2, bk1 = (c1 & 3) << 3;
    const unsigned short* Bg0 = Wot + (size_t)(colBase + ar) * DD + ak;
    const unsigned short* Bg1 = Wot + (size_t)(colBase + br1) * DD + bk1;
    const int lane = tid & 63, wv = tid >> 6;
    const int rh = wv & 1, ch = wv >> 1;
    const int fr = lane & 15, koff = (lane >> 4) << 3;
    int aoff[2], boff[4];
#pragma unroll
    for (int mi = 0; mi < 2; ++mi) aoff[mi] = (rh * 32 + mi * 16 + fr) * 32 + koff;
#pragma unroll
    for (int nj = 0; nj < 4; ++nj) boff[nj] = (ch * 64 + nj * 16 + fr) * 32 + koff;
    f32x4 acc[2][4];
#pragma unroll
    for (int mi = 0; mi < 2; ++mi)
#pragma unroll
        for (int nj = 0; nj < 4; ++nj) acc[mi][nj] = (f32x4){0.f, 0.f, 0.f, 0.f};

    // prologue: stage buffer 0
    gload16(Ag, As + tid * 8);
    gload16(Bg0, Bs + tid * 8); gload16(Bg1, Bs + c1 * 8);
    Ag += 32; Bg0 += 32; Bg1 += 32;

    for (int k0 = 0; k0 < DD; k0 += 32) {
        const int cur = (k0 >> 5) & 1;
        const int nxt = cur ^ 1;
        __syncthreads();
        if (k0 + 32 < DD) {
            gload16(Ag, As + nxt * 2048 + tid * 8);
            gload16(Bg0, Bs + nxt * 4096 + tid * 8); gload16(Bg1, Bs + nxt * 4096 + c1 * 8);
            Ag += 32; Bg0 += 32; Bg1 += 32;
        }
        const unsigned short* Ab = As + cur * 2048;
        const unsigned short* Bb = Bs + cur * 4096;
        bf16x8 av[2], bv[4];
#pragma unroll
        for (int mi = 0; mi < 2; ++mi) av[mi] = *(const bf16x8*)(Ab + aoff[mi]);
#pragma unroll
        for (int nj = 0; nj < 4; ++nj) bv[nj] = *(const bf16x8*)(Bb + boff[nj]);
#pragma unroll
        for (int mi = 0; mi < 2; ++mi)
#pragma unroll
            for (int nj = 0; nj < 4; ++nj)
                acc[mi][nj] = __builtin_amdgcn_mfma_f32_16x16x32_bf16(av[mi], bv[nj], acc[mi][nj], 0, 0, 0);
    }
    const int quad = lane >> 4;
#pragma unroll
    for (int mi = 0; mi < 2; ++mi)
#pragma unroll
        for (int i = 0; i < 4; ++i) {
            const int row = rowBase + rh * 32 + mi * 16 + quad * 4 + i;
#pragma unroll
            for (int nj = 0; nj < 4; ++nj) {
                const int col = colBase + ch * 64 + nj * 16 + fr;
                out[(size_t)row * DD + col] = acc[mi][nj][i];
            }
        }
}

// ---------------------------------------------------------------------------
extern "C" void kernel_launch(void* const* d_in, const int* in_sizes, int n_in,
                              void* d_out, int out_size, void* d_ws, size_t ws_size,
                              hipStream_t stream) {
    (void)in_sizes; (void)n_in; (void)out_size; (void)ws_size;
    const float* x  = (const float*)d_in[0];
    const float* Wq = (const float*)d_in[1];
    const float* Wk = (const float*)d_in[2];
    const float* Wv = (const float*)d_in[3];
    const float* Wo = (const float*)d_in[4];
    const float* Wb = (const float*)d_in[5];
    const float* bbp = (const float*)d_in[6];
    float* out = (float*)d_out;

    char* ws = (char*)d_ws;
    unsigned short* xb  = (unsigned short*)ws;                      ws += (size_t)MM * DD * 2;
    unsigned short* Wqt = (unsigned short*)ws;                      ws += (size_t)DD * DD * 2;
    unsigned short* Wkt = (unsigned short*)ws;                      ws += (size_t)DD * DD * 2;
    unsigned short* Wvt = (unsigned short*)ws;                      ws += (size_t)DD * DD * 2;
    unsigned short* Wot = (unsigned short*)ws;                      ws += (size_t)DD * DD * 2;
    unsigned short* Wbt = (unsigned short*)ws;                      ws += (size_t)HH * DD * 2;
    unsigned short* qb  = (unsigned short*)ws;                      ws += (size_t)MM * DD * 2;
    unsigned short* kb  = (unsigned short*)ws;                      ws += (size_t)MM * DD * 2;
    unsigned short* vb  = (unsigned short*)ws;                      ws += (size_t)MM * DD * 2;
    unsigned short* yb  = (unsigned short*)ws;                      ws += (size_t)MM * DD * 2;
    float*          beta   = (float*)ws;                            ws += (size_t)MM * HH * 4;
    unsigned short* states = (unsigned short*)ws;                   ws += (size_t)BB * HH * NCHK * 4096 * 2;

    prep_all<<<6208, 256, 0, stream>>>(x, xb, Wb, Wbt, Wq, Wk, Wv, Wo, Wqt, Wkt, Wvt, Wot);
    gemm_qkv_beta<<<400, 256, 0, stream>>>(xb, Wqt, Wkt, Wvt, Wbt, bbp, qb, kb, vb, beta);
    chunkkv_kernel<<<BB * HH * NCHK, 256, 0, stream>>>(kb, vb, beta, states);
    attn_kernel<<<BB * HH * NCHK, 256, 0, stream>>>(qb, kb, vb, beta, states, yb);
    gemm_out<<<32 * 8, 256, 0, stream>>>(yb, Wot, out);
}